// Round 1
// baseline (531.709 us; speedup 1.0000x reference)
//
#include <hip/hip_runtime.h>
#include <hip/hip_bf16.h>
#include <cstdint>
#include <cstddef>

// ---------------------------------------------------------------------------
// Transformer block: LN1 -> MHA(16 heads, no mask) -> +res -> LN2 -> GELU MLP -> +res
// B=8 T=1024 D=1024 H=16 HD=64 FF=4096.  bf16 MFMA everywhere, fp32 accum.
// ---------------------------------------------------------------------------

typedef __bf16 bf16;
typedef __bf16 bf16x8 __attribute__((ext_vector_type(8)));
typedef __bf16 bf16x4 __attribute__((ext_vector_type(4)));
typedef float  f32x4  __attribute__((ext_vector_type(4)));

#define BB    8
#define TT    1024
#define DD    1024
#define HH    16
#define HDIM  64
#define FFD   4096
#define MROWS (BB*TT)   // 8192

// async global->LDS, 16B per lane, LDS dest = wave-uniform base + lane*16
__device__ __forceinline__ void async_ld16(const void* g, void* l) {
  __builtin_amdgcn_global_load_lds(
      (const __attribute__((address_space(1))) uint32_t*)g,
      (__attribute__((address_space(3))) uint32_t*)l, 16, 0, 0);
}

// ---------------------------------------------------------------------------
// Weight repack: src (K,N) f32 row-major -> dst (N,K) bf16 row-major (B^T),
// batched over blockIdx.z (per-head for Wq/Wk/Wv).
// ---------------------------------------------------------------------------
__global__ void k_transpose_cast(const float* __restrict__ src, bf16* __restrict__ dst,
                                 int K, int N) {
  __shared__ float tile[32][33];
  const size_t boff = (size_t)blockIdx.z * K * N;
  src += boff; dst += boff;
  const int k0 = blockIdx.y * 32, n0 = blockIdx.x * 32;
  const int tx = threadIdx.x, ty = threadIdx.y; // (32,8)
#pragma unroll
  for (int i = 0; i < 4; ++i)
    tile[ty + i*8][tx] = src[(size_t)(k0 + ty + i*8) * N + n0 + tx];
  __syncthreads();
#pragma unroll
  for (int i = 0; i < 4; ++i)
    dst[(size_t)(n0 + ty + i*8) * K + k0 + tx] = (bf16)tile[tx][ty + i*8];
}

__global__ void k_concat_bias(const float* __restrict__ bq, const float* __restrict__ bk,
                              const float* __restrict__ bv, float* __restrict__ out) {
  int i = blockIdx.x * 256 + threadIdx.x; // 3072
  float v = (i < 1024) ? bq[i] : (i < 2048) ? bk[i - 1024] : bv[i - 2048];
  out[i] = v;
}

// ---------------------------------------------------------------------------
// LayerNorm: one block per row (D=1024), 256 threads, f32 in -> bf16 out
// ---------------------------------------------------------------------------
__global__ void k_layernorm(const float* __restrict__ x, const float* __restrict__ g,
                            const float* __restrict__ b, bf16* __restrict__ out) {
  const int row = blockIdx.x, tid = threadIdx.x;
  const float* xr = x + (size_t)row * DD;
  f32x4 v = *(const f32x4*)(xr + tid * 4);
  float s  = v[0] + v[1] + v[2] + v[3];
  float ss = v[0]*v[0] + v[1]*v[1] + v[2]*v[2] + v[3]*v[3];
#pragma unroll
  for (int m = 1; m < 64; m <<= 1) { s += __shfl_xor(s, m); ss += __shfl_xor(ss, m); }
  __shared__ float red[8];
  const int wid = tid >> 6;
  if ((tid & 63) == 0) { red[wid*2] = s; red[wid*2+1] = ss; }
  __syncthreads();
  s  = red[0] + red[2] + red[4] + red[6];
  ss = red[1] + red[3] + red[5] + red[7];
  const float mu = s * (1.0f / DD);
  const float var = ss * (1.0f / DD) - mu * mu;
  const float rs = rsqrtf(var + 1e-5f);
  bf16x4 o;
#pragma unroll
  for (int j = 0; j < 4; ++j)
    o[j] = (bf16)((v[j] - mu) * rs * g[tid*4 + j] + b[tid*4 + j]);
  *(bf16x4*)&out[(size_t)row * DD + tid * 4] = o;
}

// ---------------------------------------------------------------------------
// GEMM: C(M,N) = A(M,K) bf16 * Bt(N,K) bf16 + bias.
// 128x128 tile, BK=64, 4 waves (2x2), 4x4 16x16x32 frags per wave.
// global_load_lds staging with pre-swizzled source (chunk ^= row&7), swizzled reads.
// MODE 0: outb = acc+bias (bf16)
// MODE 1: outb = gelu_exact(acc+bias) (bf16)
// MODE 2: outf = acc+bias+res (f32)
// ---------------------------------------------------------------------------
template<int MODE>
__global__ __launch_bounds__(256)
void k_gemm(const bf16* __restrict__ A, const bf16* __restrict__ Bt,
            const float* __restrict__ bias, const float* __restrict__ res,
            bf16* __restrict__ outb, float* __restrict__ outf,
            int M, int N, int K) {
  __shared__ __align__(16) bf16 As[128 * 64];
  __shared__ __align__(16) bf16 Bs[128 * 64];
  const int tid = threadIdx.x;
  const int w = tid >> 6, l = tid & 63;
  const int wm = w >> 1, wn = w & 1;
  const int l15 = l & 15, l4 = l >> 4;
  const int m0 = blockIdx.y * 128, n0 = blockIdx.x * 128;

  f32x4 acc[4][4] = {};

  const int srow0 = w * 32 + (l >> 3); // staging row (8 rows per 1KB instr)
  const int sl7 = l & 7;

  for (int k0 = 0; k0 < K; k0 += 64) {
#pragma unroll
    for (int j = 0; j < 4; ++j) {
      const int row = srow0 + j * 8;
      const int ch = sl7 ^ (row & 7);
      async_ld16(A + (size_t)(m0 + row) * K + k0 + ch * 8, &As[(w*32 + j*8) * 64]);
    }
#pragma unroll
    for (int j = 0; j < 4; ++j) {
      const int row = srow0 + j * 8;
      const int ch = sl7 ^ (row & 7);
      async_ld16(Bt + (size_t)(n0 + row) * K + k0 + ch * 8, &Bs[(w*32 + j*8) * 64]);
    }
    __syncthreads();
#pragma unroll
    for (int kk = 0; kk < 2; ++kk) {
      bf16x8 af[4], bfr[4];
#pragma unroll
      for (int mf = 0; mf < 4; ++mf) {
        const int row = wm*64 + mf*16 + l15;
        const int ch = (kk*4 + l4) ^ (row & 7);
        af[mf] = *(const bf16x8*)&As[row*64 + ch*8];
      }
#pragma unroll
      for (int nf = 0; nf < 4; ++nf) {
        const int row = wn*64 + nf*16 + l15;
        const int ch = (kk*4 + l4) ^ (row & 7);
        bfr[nf] = *(const bf16x8*)&Bs[row*64 + ch*8];
      }
#pragma unroll
      for (int mf = 0; mf < 4; ++mf)
#pragma unroll
        for (int nf = 0; nf < 4; ++nf)
          acc[mf][nf] = __builtin_amdgcn_mfma_f32_16x16x32_bf16(af[mf], bfr[nf], acc[mf][nf], 0, 0, 0);
    }
    __syncthreads();
  }

#pragma unroll
  for (int mf = 0; mf < 4; ++mf) {
#pragma unroll
    for (int r = 0; r < 4; ++r) {
      const size_t grow = (size_t)(m0 + wm*64 + mf*16 + l4*4 + r);
      const size_t rowoff = grow * (size_t)N;
#pragma unroll
      for (int nf = 0; nf < 4; ++nf) {
        const int gcol = n0 + wn*64 + nf*16 + l15;
        float v = acc[mf][nf][r] + bias[gcol];
        if constexpr (MODE == 1)
          v = 0.5f * v * (1.0f + erff(v * 0.70710678118654752440f));
        if constexpr (MODE == 2) {
          v += res[rowoff + gcol];
          outf[rowoff + gcol] = v;
        } else {
          outb[rowoff + gcol] = (bf16)v;
        }
      }
    }
  }
}

// ---------------------------------------------------------------------------
// Flash attention. qkv: (B*T, 3072) bf16 rows = [Q(h*64+e) | K | V].
// Block = (q-tile of 64, head, batch); 4 waves x 16 q-rows; KV tiles of 64.
// S = Q*K^T via MFMA (K frags straight from global, contiguous in hd);
// online softmax in C-layout regs; P via padded LDS; V transposed in padded LDS.
// ---------------------------------------------------------------------------
__global__ __launch_bounds__(256)
void k_attn(const bf16* __restrict__ qkv, bf16* __restrict__ ctx) {
  const int qt = blockIdx.x, h = blockIdx.y, b = blockIdx.z;
  const int tid = threadIdx.x;
  const int w = tid >> 6, l = tid & 63;
  const int l15 = l & 15, l4 = l >> 4;

  __shared__ __align__(16) bf16 Vt[64][72];      // Vt[hd][kv], padded
  __shared__ __align__(16) bf16 P[4][16][72];    // per-wave P[qrow][kv], padded

  const bf16* base = qkv + (size_t)b * TT * 3072;
  const bf16* Qp = base + h * 64;
  const bf16* Kp = base + 1024 + h * 64;
  const bf16* Vp = base + 2048 + h * 64;

  const int qrow = qt * 64 + w * 16 + l15;
  bf16x8 qf[2];
  qf[0] = *(const bf16x8*)&Qp[(size_t)qrow * 3072 + l4 * 8];
  qf[1] = *(const bf16x8*)&Qp[(size_t)qrow * 3072 + 32 + l4 * 8];

  f32x4 oacc[4] = {};
  float mrow[4] = {-1e30f, -1e30f, -1e30f, -1e30f};
  float lrow[4] = {0.f, 0.f, 0.f, 0.f};

  for (int t = 0; t < TT / 64; ++t) {
    const int kv0 = t * 64;
    __syncthreads();           // protect Vt from previous iteration's readers
    // stage V^T (coalesced 2B reads; write conflicts acceptable this round)
    for (int idx = tid; idx < 4096; idx += 256) {
      const int hd = idx & 63, kv = idx >> 6;
      Vt[hd][kv] = Vp[(size_t)(kv0 + kv) * 3072 + hd];
    }
    // S = Q K^T  (B-frag of K^T is contiguous 16B in hd from global)
    f32x4 sacc[4] = {};
#pragma unroll
    for (int nf = 0; nf < 4; ++nf) {
#pragma unroll
      for (int kk = 0; kk < 2; ++kk) {
        bf16x8 kfr = *(const bf16x8*)&Kp[(size_t)(kv0 + nf*16 + l15) * 3072 + kk*32 + l4*8];
        sacc[nf] = __builtin_amdgcn_mfma_f32_16x16x32_bf16(qf[kk], kfr, sacc[nf], 0, 0, 0);
      }
    }
    // online softmax on C-layout rows (row = 4*l4 + r, col = l15 + 16*nf)
    float mnew[4], ef[4];
#pragma unroll
    for (int r = 0; r < 4; ++r) {
      float mx = -1e30f;
#pragma unroll
      for (int nf = 0; nf < 4; ++nf) { sacc[nf][r] *= 0.125f; mx = fmaxf(mx, sacc[nf][r]); }
      mx = fmaxf(mx, __shfl_xor(mx, 1));
      mx = fmaxf(mx, __shfl_xor(mx, 2));
      mx = fmaxf(mx, __shfl_xor(mx, 4));
      mx = fmaxf(mx, __shfl_xor(mx, 8));
      mnew[r] = fmaxf(mrow[r], mx);
      ef[r] = __expf(mrow[r] - mnew[r]);
      mrow[r] = mnew[r];
    }
#pragma unroll
    for (int r = 0; r < 4; ++r) {
      float rs = 0.f;
#pragma unroll
      for (int nf = 0; nf < 4; ++nf) {
        const float p = __expf(sacc[nf][r] - mnew[r]);
        rs += p;
        P[w][l4*4 + r][l15 + nf*16] = (bf16)p;
      }
      rs += __shfl_xor(rs, 1); rs += __shfl_xor(rs, 2);
      rs += __shfl_xor(rs, 4); rs += __shfl_xor(rs, 8);
      lrow[r] = lrow[r] * ef[r] + rs;
#pragma unroll
      for (int nf = 0; nf < 4; ++nf) oacc[nf][r] *= ef[r];
    }
    __syncthreads();           // Vt + P ready
    // O += P * V
#pragma unroll
    for (int kk = 0; kk < 2; ++kk) {
      bf16x8 pa = *(const bf16x8*)&P[w][l15][kk*32 + l4*8];
#pragma unroll
      for (int nf = 0; nf < 4; ++nf) {
        bf16x8 vb = *(const bf16x8*)&Vt[l15 + nf*16][kk*32 + l4*8];
        oacc[nf] = __builtin_amdgcn_mfma_f32_16x16x32_bf16(pa, vb, oacc[nf], 0, 0, 0);
      }
    }
  }
  // write ctx (B*T, 1024), cols h*64+e
  bf16* outp = ctx + ((size_t)b * TT + qt * 64 + w * 16) * DD + h * 64;
#pragma unroll
  for (int nf = 0; nf < 4; ++nf)
#pragma unroll
    for (int r = 0; r < 4; ++r)
      outp[(size_t)(l4*4 + r) * DD + l15 + nf*16] = (bf16)(oacc[nf][r] / lrow[r]);
}

// ---------------------------------------------------------------------------
// launch
// ---------------------------------------------------------------------------
extern "C" void kernel_launch(void* const* d_in, const int* in_sizes, int n_in,
                              void* d_out, int out_size, void* d_ws, size_t ws_size,
                              hipStream_t stream) {
  const float* x     = (const float*)d_in[0];
  const float* ln1_g = (const float*)d_in[1];
  const float* ln1_b = (const float*)d_in[2];
  const float* ln2_g = (const float*)d_in[3];
  const float* ln2_b = (const float*)d_in[4];
  const float* Wq    = (const float*)d_in[5];
  const float* bq    = (const float*)d_in[6];
  const float* Wk    = (const float*)d_in[7];
  const float* bk    = (const float*)d_in[8];
  const float* Wv    = (const float*)d_in[9];
  const float* bv    = (const float*)d_in[10];
  const float* Wo    = (const float*)d_in[11];
  const float* bo    = (const float*)d_in[12];
  const float* W1    = (const float*)d_in[13];
  const float* b1    = (const float*)d_in[14];
  const float* W2    = (const float*)d_in[15];
  const float* b2    = (const float*)d_in[16];
  float* out = (float*)d_out;

  char* ws = (char*)d_ws;
  // layout (aliased where lifetimes allow):
  bf16* h1    = (bf16*)(ws + 0);                    // 16MB, LN1 out; reused as h2
  bf16* qkv   = (bf16*)(ws + 16777216);             // 48MB
  bf16* ctx   = (bf16*)(ws + 67108864);             // 16MB
  bf16* u     = (bf16*)(ws + 16777216);             // 64MB, aliases qkv+ctx (dead)
  float* x1   = (float*)(ws + 83886080);            // 32MB
  bf16* wtqkv = (bf16*)(ws + 117440512);            // 6MB  (3072,1024)
  bf16* wot   = (bf16*)(ws + 123731968);            // 2MB  (1024,1024)
  bf16* w1t   = (bf16*)(ws + 125829120);            // 8MB  (4096,1024)
  bf16* w2t   = (bf16*)(ws + 134217728);            // 8MB  (1024,4096)
  float* bqkv = (float*)(ws + 142606336);           // 12KB (3072)
  bf16* h2 = h1;

  dim3 tb(32, 8);
  // per-head (D,HD) transposes for Q/K/V -> rows of (3072,1024)
  k_transpose_cast<<<dim3(2, 32, 16), tb, 0, stream>>>(Wq, wtqkv, DD, HDIM);
  k_transpose_cast<<<dim3(2, 32, 16), tb, 0, stream>>>(Wk, wtqkv + 1024*1024, DD, HDIM);
  k_transpose_cast<<<dim3(2, 32, 16), tb, 0, stream>>>(Wv, wtqkv + 2048*1024, DD, HDIM);
  k_transpose_cast<<<dim3(32, 32, 1), tb, 0, stream>>>(Wo, wot, DD, DD);
  k_transpose_cast<<<dim3(128, 32, 1), tb, 0, stream>>>(W1, w1t, DD, FFD);
  k_transpose_cast<<<dim3(32, 128, 1), tb, 0, stream>>>(W2, w2t, FFD, DD);
  k_concat_bias<<<dim3(12), 256, 0, stream>>>(bq, bk, bv, bqkv);

  k_layernorm<<<dim3(MROWS), 256, 0, stream>>>(x, ln1_g, ln1_b, h1);

  // QKV: (8192,1024) x (3072,1024)^T -> qkv bf16
  k_gemm<0><<<dim3(24, 64), 256, 0, stream>>>(h1, wtqkv, bqkv, nullptr,
                                              qkv, nullptr, MROWS, 3072, DD);

  k_attn<<<dim3(16, 16, 8), 256, 0, stream>>>(qkv, ctx);

  // Wo + residual: x1 = x + ctx@Wo + bo  (f32)
  k_gemm<2><<<dim3(8, 64), 256, 0, stream>>>(ctx, wot, bo, x,
                                             nullptr, x1, MROWS, DD, DD);

  k_layernorm<<<dim3(MROWS), 256, 0, stream>>>(x1, ln2_g, ln2_b, h2);

  // FF1 + exact GELU -> u bf16
  k_gemm<1><<<dim3(32, 64), 256, 0, stream>>>(h2, w1t, b1, nullptr,
                                              u, nullptr, MROWS, FFD, DD);

  // FF2 + residual -> out f32
  k_gemm<2><<<dim3(8, 64), 256, 0, stream>>>(u, w2t, b2, x1,
                                             nullptr, out, MROWS, DD, FFD);

  (void)in_sizes; (void)n_in; (void)out_size; (void)ws_size;
}

// Round 2
// 479.526 us; speedup vs baseline: 1.1088x; 1.1088x over previous
//
#include <hip/hip_runtime.h>
#include <hip/hip_bf16.h>
#include <cstdint>
#include <cstddef>

// ---------------------------------------------------------------------------
// Transformer block: LN1 -> MHA(16 heads, no mask) -> +res -> LN2 -> GELU MLP -> +res
// B=8 T=1024 D=1024 H=16 HD=64 FF=4096.  bf16 MFMA everywhere, fp32 accum.
// ---------------------------------------------------------------------------

typedef __bf16 bf16;
typedef __bf16 bf16x8 __attribute__((ext_vector_type(8)));
typedef __bf16 bf16x4 __attribute__((ext_vector_type(4)));
typedef float  f32x4  __attribute__((ext_vector_type(4)));

#define BB    8
#define TT    1024
#define DD    1024
#define HH    16
#define HDIM  64
#define FFD   4096
#define MROWS (BB*TT)   // 8192

// async global->LDS, 16B per lane, LDS dest = wave-uniform base + lane*16
__device__ __forceinline__ void async_ld16(const void* g, void* l) {
  __builtin_amdgcn_global_load_lds(
      (const __attribute__((address_space(1))) uint32_t*)g,
      (__attribute__((address_space(3))) uint32_t*)l, 16, 0, 0);
}

// ---------------------------------------------------------------------------
// Weight repack: src (K,N) f32 row-major -> dst (N,K) bf16 row-major (B^T),
// batched over blockIdx.z (per-head for Wq/Wk/Wv).
// ---------------------------------------------------------------------------
__global__ void k_transpose_cast(const float* __restrict__ src, bf16* __restrict__ dst,
                                 int K, int N) {
  __shared__ float tile[32][33];
  const size_t boff = (size_t)blockIdx.z * K * N;
  src += boff; dst += boff;
  const int k0 = blockIdx.y * 32, n0 = blockIdx.x * 32;
  const int tx = threadIdx.x, ty = threadIdx.y; // (32,8)
#pragma unroll
  for (int i = 0; i < 4; ++i)
    tile[ty + i*8][tx] = src[(size_t)(k0 + ty + i*8) * N + n0 + tx];
  __syncthreads();
#pragma unroll
  for (int i = 0; i < 4; ++i)
    dst[(size_t)(n0 + ty + i*8) * K + k0 + tx] = (bf16)tile[tx][ty + i*8];
}

__global__ void k_concat_bias(const float* __restrict__ bq, const float* __restrict__ bk,
                              const float* __restrict__ bv, float* __restrict__ out) {
  int i = blockIdx.x * 256 + threadIdx.x; // 3072
  float v = (i < 1024) ? bq[i] : (i < 2048) ? bk[i - 1024] : bv[i - 2048];
  out[i] = v;
}

// V part of qkv (B*T, 3072) -> vT[b][h][e][t]  (per-(b,h) 64x1024, t contiguous)
__global__ void k_transpose_v(const bf16* __restrict__ qkv, bf16* __restrict__ vT) {
  __shared__ bf16 tile[32][33];
  const int bh = blockIdx.z;          // b*16+h
  const int b = bh >> 4, h = bh & 15;
  const int t0 = blockIdx.x * 32, e0 = blockIdx.y * 32;
  const int tx = threadIdx.x, ty = threadIdx.y; // (32,8)
  const bf16* src = qkv + (size_t)b * TT * 3072 + 2048 + h * 64;
#pragma unroll
  for (int i = 0; i < 4; ++i)
    tile[ty + i*8][tx] = src[(size_t)(t0 + ty + i*8) * 3072 + e0 + tx];
  __syncthreads();
  bf16* dst = vT + ((size_t)bh * 64 + e0) * TT + t0;
#pragma unroll
  for (int i = 0; i < 4; ++i)
    dst[(size_t)(ty + i*8) * TT + tx] = tile[tx][ty + i*8];
}

// ---------------------------------------------------------------------------
// LayerNorm: one block per row (D=1024), 256 threads, f32 in -> bf16 out
// ---------------------------------------------------------------------------
__global__ void k_layernorm(const float* __restrict__ x, const float* __restrict__ g,
                            const float* __restrict__ b, bf16* __restrict__ out) {
  const int row = blockIdx.x, tid = threadIdx.x;
  const float* xr = x + (size_t)row * DD;
  f32x4 v = *(const f32x4*)(xr + tid * 4);
  float s  = v[0] + v[1] + v[2] + v[3];
  float ss = v[0]*v[0] + v[1]*v[1] + v[2]*v[2] + v[3]*v[3];
#pragma unroll
  for (int m = 1; m < 64; m <<= 1) { s += __shfl_xor(s, m); ss += __shfl_xor(ss, m); }
  __shared__ float red[8];
  const int wid = tid >> 6;
  if ((tid & 63) == 0) { red[wid*2] = s; red[wid*2+1] = ss; }
  __syncthreads();
  s  = red[0] + red[2] + red[4] + red[6];
  ss = red[1] + red[3] + red[5] + red[7];
  const float mu = s * (1.0f / DD);
  const float var = ss * (1.0f / DD) - mu * mu;
  const float rs = rsqrtf(var + 1e-5f);
  bf16x4 o;
#pragma unroll
  for (int j = 0; j < 4; ++j)
    o[j] = (bf16)((v[j] - mu) * rs * g[tid*4 + j] + b[tid*4 + j]);
  *(bf16x4*)&out[(size_t)row * DD + tid * 4] = o;
}

// ---------------------------------------------------------------------------
// GEMM: C(M,N) = A(M,K) bf16 * Bt(N,K) bf16 + bias.
// 128x128 tile, BK=64, 4 waves (2x2), 4x4 16x16x32 frags per wave.
// global_load_lds staging with pre-swizzled source (chunk ^= row&7), swizzled reads.
// MODE 0: outb = acc+bias (bf16)
// MODE 1: outb = gelu_exact(acc+bias) (bf16)
// MODE 2: outf = acc+bias+res (f32)
// ---------------------------------------------------------------------------
template<int MODE>
__global__ __launch_bounds__(256)
void k_gemm(const bf16* __restrict__ A, const bf16* __restrict__ Bt,
            const float* __restrict__ bias, const float* __restrict__ res,
            bf16* __restrict__ outb, float* __restrict__ outf,
            int M, int N, int K) {
  __shared__ __align__(16) bf16 As[128 * 64];
  __shared__ __align__(16) bf16 Bs[128 * 64];
  const int tid = threadIdx.x;
  const int w = tid >> 6, l = tid & 63;
  const int wm = w >> 1, wn = w & 1;
  const int l15 = l & 15, l4 = l >> 4;
  const int m0 = blockIdx.y * 128, n0 = blockIdx.x * 128;

  f32x4 acc[4][4] = {};

  const int srow0 = w * 32 + (l >> 3); // staging row (8 rows per 1KB instr)
  const int sl7 = l & 7;

  for (int k0 = 0; k0 < K; k0 += 64) {
#pragma unroll
    for (int j = 0; j < 4; ++j) {
      const int row = srow0 + j * 8;
      const int ch = sl7 ^ (row & 7);
      async_ld16(A + (size_t)(m0 + row) * K + k0 + ch * 8, &As[(w*32 + j*8) * 64]);
    }
#pragma unroll
    for (int j = 0; j < 4; ++j) {
      const int row = srow0 + j * 8;
      const int ch = sl7 ^ (row & 7);
      async_ld16(Bt + (size_t)(n0 + row) * K + k0 + ch * 8, &Bs[(w*32 + j*8) * 64]);
    }
    __syncthreads();
#pragma unroll
    for (int kk = 0; kk < 2; ++kk) {
      bf16x8 af[4], bfr[4];
#pragma unroll
      for (int mf = 0; mf < 4; ++mf) {
        const int row = wm*64 + mf*16 + l15;
        const int ch = (kk*4 + l4) ^ (row & 7);
        af[mf] = *(const bf16x8*)&As[row*64 + ch*8];
      }
#pragma unroll
      for (int nf = 0; nf < 4; ++nf) {
        const int row = wn*64 + nf*16 + l15;
        const int ch = (kk*4 + l4) ^ (row & 7);
        bfr[nf] = *(const bf16x8*)&Bs[row*64 + ch*8];
      }
#pragma unroll
      for (int mf = 0; mf < 4; ++mf)
#pragma unroll
        for (int nf = 0; nf < 4; ++nf)
          acc[mf][nf] = __builtin_amdgcn_mfma_f32_16x16x32_bf16(af[mf], bfr[nf], acc[mf][nf], 0, 0, 0);
    }
    __syncthreads();
  }

#pragma unroll
  for (int mf = 0; mf < 4; ++mf) {
#pragma unroll
    for (int r = 0; r < 4; ++r) {
      const size_t grow = (size_t)(m0 + wm*64 + mf*16 + l4*4 + r);
      const size_t rowoff = grow * (size_t)N;
#pragma unroll
      for (int nf = 0; nf < 4; ++nf) {
        const int gcol = n0 + wn*64 + nf*16 + l15;
        float v = acc[mf][nf][r] + bias[gcol];
        if constexpr (MODE == 1)
          v = 0.5f * v * (1.0f + erff(v * 0.70710678118654752440f));
        if constexpr (MODE == 2) {
          v += res[rowoff + gcol];
          outf[rowoff + gcol] = v;
        } else {
          outb[rowoff + gcol] = (bf16)v;
        }
      }
    }
  }
}

// ---------------------------------------------------------------------------
// Flash attention v2. qkv: (B*T, 3072) bf16 rows = [Q | K | V]; vT[b][h][e][t].
// Block = (q-tile of 64, head, batch); 4 waves x 16 q-rows; KV tiles of 64.
// K-tile and V^T-tile async-staged into double-buffered swizzled LDS (shared
// by all 4 waves). P is wave-private LDS -> only ONE barrier per KV tile;
// stage(t+1) issued after the barrier so it flies under compute(t).
// ---------------------------------------------------------------------------
__global__ __launch_bounds__(256)
void k_attn(const bf16* __restrict__ qkv, const bf16* __restrict__ vT,
            bf16* __restrict__ ctx) {
  const int qt = blockIdx.x, h = blockIdx.y, b = blockIdx.z;
  const int tid = threadIdx.x;
  const int w = tid >> 6, l = tid & 63;
  const int l15 = l & 15, l4 = l >> 4;

  __shared__ __align__(16) bf16 Ks[2][64 * 64];   // [kv][hd] swizzled
  __shared__ __align__(16) bf16 Vs[2][64 * 64];   // [e][kv]  swizzled
  __shared__ __align__(16) bf16 P[4][16][72];     // wave-private P[q][kv]

  const bf16* base = qkv + (size_t)b * TT * 3072;
  const bf16* Qp = base + h * 64;
  const bf16* Kp = base + 1024 + h * 64;
  const bf16* Vtp = vT + ((size_t)(b * HH + h)) * HDIM * TT;

  const int qrow = qt * 64 + w * 16 + l15;
  bf16x8 qf[2];
  qf[0] = *(const bf16x8*)&Qp[(size_t)qrow * 3072 + l4 * 8];
  qf[1] = *(const bf16x8*)&Qp[(size_t)qrow * 3072 + 32 + l4 * 8];

  f32x4 oacc[4] = {};
  float mrow[4] = {-1e30f, -1e30f, -1e30f, -1e30f};
  float lrow[4] = {0.f, 0.f, 0.f, 0.f};

  const int sr = (l >> 3);       // staging sub-row 0..7
  const int sl7 = l & 7;

  auto stage = [&](int buf, int t) {
    const int kv0 = t * 64;
#pragma unroll
    for (int j = 0; j < 2; ++j) {
      const int row = w*16 + j*8 + sr;
      const int ch = sl7 ^ (row & 7);
      async_ld16(Kp + (size_t)(kv0 + row) * 3072 + ch * 8, &Ks[buf][(w*16 + j*8) * 64]);
    }
#pragma unroll
    for (int j = 0; j < 2; ++j) {
      const int row = w*16 + j*8 + sr;
      const int ch = sl7 ^ (row & 7);
      async_ld16(Vtp + (size_t)row * TT + kv0 + ch * 8, &Vs[buf][(w*16 + j*8) * 64]);
    }
  };

  stage(0, 0);
  for (int t = 0; t < TT / 64; ++t) {
    const int cur = t & 1;
    __syncthreads();                    // drains stage(t) -> buf[cur] ready
    if (t + 1 < TT / 64) stage(cur ^ 1, t + 1);   // flies under compute(t)

    // S = Q K^T
    f32x4 sacc[4] = {};
#pragma unroll
    for (int nf = 0; nf < 4; ++nf) {
      const int row = nf*16 + l15;
#pragma unroll
      for (int kk = 0; kk < 2; ++kk) {
        const int ch = (kk*4 + l4) ^ (row & 7);
        bf16x8 kfr = *(const bf16x8*)&Ks[cur][row*64 + ch*8];
        sacc[nf] = __builtin_amdgcn_mfma_f32_16x16x32_bf16(qf[kk], kfr, sacc[nf], 0, 0, 0);
      }
    }
    // online softmax on C-layout rows (row = 4*l4 + r, col = l15 + 16*nf)
    float mnew[4], ef[4];
#pragma unroll
    for (int r = 0; r < 4; ++r) {
      float mx = -1e30f;
#pragma unroll
      for (int nf = 0; nf < 4; ++nf) { sacc[nf][r] *= 0.125f; mx = fmaxf(mx, sacc[nf][r]); }
      mx = fmaxf(mx, __shfl_xor(mx, 1));
      mx = fmaxf(mx, __shfl_xor(mx, 2));
      mx = fmaxf(mx, __shfl_xor(mx, 4));
      mx = fmaxf(mx, __shfl_xor(mx, 8));
      mnew[r] = fmaxf(mrow[r], mx);
      ef[r] = __expf(mrow[r] - mnew[r]);
      mrow[r] = mnew[r];
    }
#pragma unroll
    for (int r = 0; r < 4; ++r) {
      float rs = 0.f;
#pragma unroll
      for (int nf = 0; nf < 4; ++nf) {
        const float p = __expf(sacc[nf][r] - mnew[r]);
        rs += p;
        P[w][l4*4 + r][l15 + nf*16] = (bf16)p;
      }
      rs += __shfl_xor(rs, 1); rs += __shfl_xor(rs, 2);
      rs += __shfl_xor(rs, 4); rs += __shfl_xor(rs, 8);
      lrow[r] = lrow[r] * ef[r] + rs;
#pragma unroll
      for (int nf = 0; nf < 4; ++nf) oacc[nf][r] *= ef[r];
    }
    // O += P * V   (P wave-private: no barrier needed, compiler waits lgkmcnt)
#pragma unroll
    for (int kk = 0; kk < 2; ++kk) {
      bf16x8 pa = *(const bf16x8*)&P[w][l15][kk*32 + l4*8];
#pragma unroll
      for (int nf = 0; nf < 4; ++nf) {
        const int row = nf*16 + l15;
        const int ch = (kk*4 + l4) ^ (row & 7);
        bf16x8 vb = *(const bf16x8*)&Vs[cur][row*64 + ch*8];
        oacc[nf] = __builtin_amdgcn_mfma_f32_16x16x32_bf16(pa, vb, oacc[nf], 0, 0, 0);
      }
    }
  }
  // write ctx (B*T, 1024), cols h*64+e
  bf16* outp = ctx + ((size_t)b * TT + qt * 64 + w * 16) * DD + h * 64;
#pragma unroll
  for (int nf = 0; nf < 4; ++nf)
#pragma unroll
    for (int r = 0; r < 4; ++r)
      outp[(size_t)(l4*4 + r) * DD + l15 + nf*16] = (bf16)(oacc[nf][r] / lrow[r]);
}

// ---------------------------------------------------------------------------
// launch
// ---------------------------------------------------------------------------
extern "C" void kernel_launch(void* const* d_in, const int* in_sizes, int n_in,
                              void* d_out, int out_size, void* d_ws, size_t ws_size,
                              hipStream_t stream) {
  const float* x     = (const float*)d_in[0];
  const float* ln1_g = (const float*)d_in[1];
  const float* ln1_b = (const float*)d_in[2];
  const float* ln2_g = (const float*)d_in[3];
  const float* ln2_b = (const float*)d_in[4];
  const float* Wq    = (const float*)d_in[5];
  const float* bq    = (const float*)d_in[6];
  const float* Wk    = (const float*)d_in[7];
  const float* bk    = (const float*)d_in[8];
  const float* Wv    = (const float*)d_in[9];
  const float* bv    = (const float*)d_in[10];
  const float* Wo    = (const float*)d_in[11];
  const float* bo    = (const float*)d_in[12];
  const float* W1    = (const float*)d_in[13];
  const float* b1    = (const float*)d_in[14];
  const float* W2    = (const float*)d_in[15];
  const float* b2    = (const float*)d_in[16];
  float* out = (float*)d_out;

  char* ws = (char*)d_ws;
  // layout (aliased where lifetimes allow):
  bf16* h1    = (bf16*)(ws + 0);                    // 16MB, LN1 out (dead after QKV GEMM)
  bf16* vT    = (bf16*)(ws + 0);                    // 16MB, aliases h1 (lives during attn)
  bf16* qkv   = (bf16*)(ws + 16777216);             // 48MB
  bf16* ctx   = (bf16*)(ws + 67108864);             // 16MB
  bf16* u     = (bf16*)(ws + 16777216);             // 64MB, aliases qkv+ctx (dead)
  float* x1   = (float*)(ws + 83886080);            // 32MB
  bf16* wtqkv = (bf16*)(ws + 117440512);            // 6MB  (3072,1024)
  bf16* wot   = (bf16*)(ws + 123731968);            // 2MB  (1024,1024)
  bf16* w1t   = (bf16*)(ws + 125829120);            // 8MB  (4096,1024)
  bf16* w2t   = (bf16*)(ws + 134217728);            // 8MB  (1024,4096)
  float* bqkv = (float*)(ws + 142606336);           // 12KB (3072)
  bf16* h2 = h1;                                    // LN2 out (after attn, vT dead)

  dim3 tb(32, 8);
  // per-head (D,HD) transposes for Q/K/V -> rows of (3072,1024)
  k_transpose_cast<<<dim3(2, 32, 16), tb, 0, stream>>>(Wq, wtqkv, DD, HDIM);
  k_transpose_cast<<<dim3(2, 32, 16), tb, 0, stream>>>(Wk, wtqkv + 1024*1024, DD, HDIM);
  k_transpose_cast<<<dim3(2, 32, 16), tb, 0, stream>>>(Wv, wtqkv + 2048*1024, DD, HDIM);
  k_transpose_cast<<<dim3(32, 32, 1), tb, 0, stream>>>(Wo, wot, DD, DD);
  k_transpose_cast<<<dim3(128, 32, 1), tb, 0, stream>>>(W1, w1t, DD, FFD);
  k_transpose_cast<<<dim3(32, 128, 1), tb, 0, stream>>>(W2, w2t, FFD, DD);
  k_concat_bias<<<dim3(12), 256, 0, stream>>>(bq, bk, bv, bqkv);

  k_layernorm<<<dim3(MROWS), 256, 0, stream>>>(x, ln1_g, ln1_b, h1);

  // QKV: (8192,1024) x (3072,1024)^T -> qkv bf16
  k_gemm<0><<<dim3(24, 64), 256, 0, stream>>>(h1, wtqkv, bqkv, nullptr,
                                              qkv, nullptr, MROWS, 3072, DD);

  // V -> vT[b][h][e][t]  (h1 dead now; vT aliases it)
  k_transpose_v<<<dim3(32, 2, 128), tb, 0, stream>>>(qkv, vT);

  k_attn<<<dim3(16, 16, 8), 256, 0, stream>>>(qkv, vT, ctx);

  // Wo + residual: x1 = x + ctx@Wo + bo  (f32)
  k_gemm<2><<<dim3(8, 64), 256, 0, stream>>>(ctx, wot, bo, x,
                                             nullptr, x1, MROWS, DD, DD);

  k_layernorm<<<dim3(MROWS), 256, 0, stream>>>(x1, ln2_g, ln2_b, h2);

  // FF1 + exact GELU -> u bf16
  k_gemm<1><<<dim3(32, 64), 256, 0, stream>>>(h2, w1t, b1, nullptr,
                                              u, nullptr, MROWS, FFD, DD);

  // FF2 + residual -> out f32
  k_gemm<2><<<dim3(8, 64), 256, 0, stream>>>(u, w2t, b2, x1,
                                             nullptr, out, MROWS, DD, FFD);

  (void)in_sizes; (void)n_in; (void)out_size; (void)ws_size;
}

// Round 3
// 472.259 us; speedup vs baseline: 1.1259x; 1.0154x over previous
//
#include <hip/hip_runtime.h>
#include <hip/hip_bf16.h>
#include <cstdint>
#include <cstddef>

// ---------------------------------------------------------------------------
// Transformer block: LN1 -> MHA(16 heads, no mask) -> +res -> LN2 -> GELU MLP -> +res
// B=8 T=1024 D=1024 H=16 HD=64 FF=4096.  bf16 MFMA everywhere, fp32 accum.
// ---------------------------------------------------------------------------

typedef __bf16 bf16;
typedef __bf16 bf16x8 __attribute__((ext_vector_type(8)));
typedef __bf16 bf16x4 __attribute__((ext_vector_type(4)));
typedef float  f32x4  __attribute__((ext_vector_type(4)));

#define BB    8
#define TT    1024
#define DD    1024
#define HH    16
#define HDIM  64
#define FFD   4096
#define MROWS (BB*TT)   // 8192

// async global->LDS, 16B per lane, LDS dest = wave-uniform base + lane*16
__device__ __forceinline__ void async_ld16(const void* g, void* l) {
  __builtin_amdgcn_global_load_lds(
      (const __attribute__((address_space(1))) uint32_t*)g,
      (__attribute__((address_space(3))) uint32_t*)l, 16, 0, 0);
}

// ---------------------------------------------------------------------------
// Weight repack: src (K,N) f32 row-major -> dst (N,K) bf16 row-major (B^T),
// batched over blockIdx.z (per-head for Wq/Wk/Wv).
// ---------------------------------------------------------------------------
__global__ void k_transpose_cast(const float* __restrict__ src, bf16* __restrict__ dst,
                                 int K, int N) {
  __shared__ float tile[32][33];
  const size_t boff = (size_t)blockIdx.z * K * N;
  src += boff; dst += boff;
  const int k0 = blockIdx.y * 32, n0 = blockIdx.x * 32;
  const int tx = threadIdx.x, ty = threadIdx.y; // (32,8)
#pragma unroll
  for (int i = 0; i < 4; ++i)
    tile[ty + i*8][tx] = src[(size_t)(k0 + ty + i*8) * N + n0 + tx];
  __syncthreads();
#pragma unroll
  for (int i = 0; i < 4; ++i)
    dst[(size_t)(n0 + ty + i*8) * K + k0 + tx] = (bf16)tile[tx][ty + i*8];
}

__global__ void k_concat_bias(const float* __restrict__ bq, const float* __restrict__ bk,
                              const float* __restrict__ bv, float* __restrict__ out) {
  int i = blockIdx.x * 256 + threadIdx.x; // 3072
  float v = (i < 1024) ? bq[i] : (i < 2048) ? bk[i - 1024] : bv[i - 2048];
  out[i] = v;
}

// V part of qkv (B*T, 3072) -> vT[b][h][e][t]  (per-(b,h) 64x1024, t contiguous)
__global__ void k_transpose_v(const bf16* __restrict__ qkv, bf16* __restrict__ vT) {
  __shared__ bf16 tile[32][33];
  const int bh = blockIdx.z;          // b*16+h
  const int b = bh >> 4, h = bh & 15;
  const int t0 = blockIdx.x * 32, e0 = blockIdx.y * 32;
  const int tx = threadIdx.x, ty = threadIdx.y; // (32,8)
  const bf16* src = qkv + (size_t)b * TT * 3072 + 2048 + h * 64;
#pragma unroll
  for (int i = 0; i < 4; ++i)
    tile[ty + i*8][tx] = src[(size_t)(t0 + ty + i*8) * 3072 + e0 + tx];
  __syncthreads();
  bf16* dst = vT + ((size_t)bh * 64 + e0) * TT + t0;
#pragma unroll
  for (int i = 0; i < 4; ++i)
    dst[(size_t)(ty + i*8) * TT + tx] = tile[tx][ty + i*8];
}

// ---------------------------------------------------------------------------
// LayerNorm: one block per row (D=1024), 256 threads, f32 in -> bf16 out
// ---------------------------------------------------------------------------
__global__ void k_layernorm(const float* __restrict__ x, const float* __restrict__ g,
                            const float* __restrict__ b, bf16* __restrict__ out) {
  const int row = blockIdx.x, tid = threadIdx.x;
  const float* xr = x + (size_t)row * DD;
  f32x4 v = *(const f32x4*)(xr + tid * 4);
  float s  = v[0] + v[1] + v[2] + v[3];
  float ss = v[0]*v[0] + v[1]*v[1] + v[2]*v[2] + v[3]*v[3];
#pragma unroll
  for (int m = 1; m < 64; m <<= 1) { s += __shfl_xor(s, m); ss += __shfl_xor(ss, m); }
  __shared__ float red[8];
  const int wid = tid >> 6;
  if ((tid & 63) == 0) { red[wid*2] = s; red[wid*2+1] = ss; }
  __syncthreads();
  s  = red[0] + red[2] + red[4] + red[6];
  ss = red[1] + red[3] + red[5] + red[7];
  const float mu = s * (1.0f / DD);
  const float var = ss * (1.0f / DD) - mu * mu;
  const float rs = rsqrtf(var + 1e-5f);
  bf16x4 o;
#pragma unroll
  for (int j = 0; j < 4; ++j)
    o[j] = (bf16)((v[j] - mu) * rs * g[tid*4 + j] + b[tid*4 + j]);
  *(bf16x4*)&out[(size_t)row * DD + tid * 4] = o;
}

// ---------------------------------------------------------------------------
// 256x256-tile 8-wave phase-split GEMM (T2+T3+T4+T5).  C = A(M,K) * Bt(N,K)^T.
// BK=64, 2 K-tile double-buffered LDS (128 KiB), 4 phases/K-tile:
//   P1: ds_read k0 frags, stage Bh0(t+1);  MFMA k0 x Mfrags0-3
//   P2: ds_read k1 frags, stage Bh1(t+1);  MFMA k0 x Mfrags4-7   (all reads drained)
//   P3: stage Ah0(t+2) into buf[p] (safe: all buf[p] reads done); MFMA k1 x M0-3
//   P4: stage Ah1(t+2);                    MFMA k1 x M4-7; vmcnt(4); barrier
// Boundary vmcnt(4): tile t+1 fully arrived, t+2's A-halves stay in flight.
// MODE 0: outb = acc+bias (bf16);  MODE 1: outb = gelu_exact(acc+bias) (bf16)
// ---------------------------------------------------------------------------
template<int MODE>
__global__ __launch_bounds__(512, 2)
void k_gemm256(const bf16* __restrict__ A, const bf16* __restrict__ Bt,
               const float* __restrict__ bias, bf16* __restrict__ outb,
               int M, int N, int K) {
  __shared__ __align__(16) bf16 As[2][256 * 64];
  __shared__ __align__(16) bf16 Bs[2][256 * 64];
  const int tid = threadIdx.x;
  const int w = tid >> 6, l = tid & 63;
  const int wm = w >> 2, wn = w & 3;            // 2 x 4 waves
  const int l15 = l & 15, l4 = l >> 4;

  // XCD-aware swizzle (nwg % 8 == 0 for all our shapes)
  const int nbx = N >> 8;
  const int nwg = gridDim.x;
  const int cpx = nwg >> 3;
  const int swz = (blockIdx.x & 7) * cpx + (blockIdx.x >> 3);
  const int m0 = (swz / nbx) << 8, n0 = (swz % nbx) << 8;

  f32x4 acc[8][4] = {};

  const int srow = l >> 3;     // 0..7
  const int sch = l & 7;

  const int NT = K >> 6;

#define STAGE_A(buf, kt, rb) { \
    const int r_ = (rb) + w*8 + srow; \
    const int ch_ = sch ^ (r_ & 7); \
    async_ld16(A + (size_t)(m0 + r_) * K + (kt)*64 + ch_*8, &As[buf][((rb) + w*8)*64]); }
#define STAGE_B(buf, kt, rb) { \
    const int r_ = (rb) + w*8 + srow; \
    const int ch_ = sch ^ (r_ & 7); \
    async_ld16(Bt + (size_t)(n0 + r_) * K + (kt)*64 + ch_*8, &Bs[buf][((rb) + w*8)*64]); }

  // prologue: tile0 (all 4 half-tiles) + tile1 A-halves  -> 12 loads
  STAGE_A(0, 0, 0)   STAGE_A(0, 0, 64)  STAGE_A(0, 0, 128) STAGE_A(0, 0, 192)
  STAGE_B(0, 0, 0)   STAGE_B(0, 0, 64)  STAGE_B(0, 0, 128) STAGE_B(0, 0, 192)
  STAGE_A(1, 1, 0)   STAGE_A(1, 1, 64)  STAGE_A(1, 1, 128) STAGE_A(1, 1, 192)
  asm volatile("s_waitcnt vmcnt(4)" ::: "memory");
  __builtin_amdgcn_sched_barrier(0);
  __builtin_amdgcn_s_barrier();

  for (int t = 0; t < NT; ++t) {
    const int p = t & 1;
    bf16x8 a0[8], b0[4], a1[8], b1[4];

    // ---- P1: read k0 frags; stage Bh0(t+1) ----
#pragma unroll
    for (int mf = 0; mf < 8; ++mf) {
      const int row = wm*128 + mf*16 + l15;
      const int ch = l4 ^ (row & 7);
      a0[mf] = *(const bf16x8*)&As[p][row*64 + ch*8];
    }
#pragma unroll
    for (int nf = 0; nf < 4; ++nf) {
      const int row = wn*64 + nf*16 + l15;
      const int ch = l4 ^ (row & 7);
      b0[nf] = *(const bf16x8*)&Bs[p][row*64 + ch*8];
    }
    if (t + 1 < NT) { STAGE_B(p^1, t+1, 0) STAGE_B(p^1, t+1, 64) }
    __builtin_amdgcn_s_barrier();
    asm volatile("s_waitcnt lgkmcnt(0)" ::: "memory");
    __builtin_amdgcn_sched_barrier(0);
    __builtin_amdgcn_s_setprio(1);
#pragma unroll
    for (int mf = 0; mf < 4; ++mf)
#pragma unroll
      for (int nf = 0; nf < 4; ++nf)
        acc[mf][nf] = __builtin_amdgcn_mfma_f32_16x16x32_bf16(a0[mf], b0[nf], acc[mf][nf], 0, 0, 0);
    __builtin_amdgcn_s_setprio(0);
    __builtin_amdgcn_s_barrier();

    // ---- P2: read k1 frags; stage Bh1(t+1); MFMA k0 x M4-7 ----
#pragma unroll
    for (int mf = 0; mf < 8; ++mf) {
      const int row = wm*128 + mf*16 + l15;
      const int ch = (4 + l4) ^ (row & 7);
      a1[mf] = *(const bf16x8*)&As[p][row*64 + ch*8];
    }
#pragma unroll
    for (int nf = 0; nf < 4; ++nf) {
      const int row = wn*64 + nf*16 + l15;
      const int ch = (4 + l4) ^ (row & 7);
      b1[nf] = *(const bf16x8*)&Bs[p][row*64 + ch*8];
    }
    if (t + 1 < NT) { STAGE_B(p^1, t+1, 128) STAGE_B(p^1, t+1, 192) }
    __builtin_amdgcn_s_barrier();
    asm volatile("s_waitcnt lgkmcnt(0)" ::: "memory");   // ALL buf[p] reads done
    __builtin_amdgcn_sched_barrier(0);
    __builtin_amdgcn_s_setprio(1);
#pragma unroll
    for (int mf = 4; mf < 8; ++mf)
#pragma unroll
      for (int nf = 0; nf < 4; ++nf)
        acc[mf][nf] = __builtin_amdgcn_mfma_f32_16x16x32_bf16(a0[mf], b0[nf], acc[mf][nf], 0, 0, 0);
    __builtin_amdgcn_s_setprio(0);
    __builtin_amdgcn_s_barrier();   // after this barrier nobody reads buf[p] again

    // ---- P3: stage Ah0(t+2) into buf[p]; MFMA k1 x M0-3 ----
    if (t + 2 < NT) { STAGE_A(p, t+2, 0) STAGE_A(p, t+2, 64) }
    __builtin_amdgcn_s_barrier();
    __builtin_amdgcn_s_setprio(1);
#pragma unroll
    for (int mf = 0; mf < 4; ++mf)
#pragma unroll
      for (int nf = 0; nf < 4; ++nf)
        acc[mf][nf] = __builtin_amdgcn_mfma_f32_16x16x32_bf16(a1[mf], b1[nf], acc[mf][nf], 0, 0, 0);
    __builtin_amdgcn_s_setprio(0);
    __builtin_amdgcn_s_barrier();

    // ---- P4: stage Ah1(t+2); MFMA k1 x M4-7; boundary wait ----
    if (t + 2 < NT) { STAGE_A(p, t+2, 128) STAGE_A(p, t+2, 192) }
    __builtin_amdgcn_s_barrier();
    __builtin_amdgcn_s_setprio(1);
#pragma unroll
    for (int mf = 4; mf < 8; ++mf)
#pragma unroll
      for (int nf = 0; nf < 4; ++nf)
        acc[mf][nf] = __builtin_amdgcn_mfma_f32_16x16x32_bf16(a1[mf], b1[nf], acc[mf][nf], 0, 0, 0);
    __builtin_amdgcn_s_setprio(0);
    if (t < NT - 2) { asm volatile("s_waitcnt vmcnt(4)" ::: "memory"); }
    else            { asm volatile("s_waitcnt vmcnt(0)" ::: "memory"); }
    __builtin_amdgcn_sched_barrier(0);
    __builtin_amdgcn_s_barrier();   // tile t+1 visible to all waves
  }
#undef STAGE_A
#undef STAGE_B

  // epilogue
#pragma unroll
  for (int mf = 0; mf < 8; ++mf) {
#pragma unroll
    for (int r = 0; r < 4; ++r) {
      const size_t grow = (size_t)(m0 + wm*128 + mf*16 + l4*4 + r);
      const size_t rowoff = grow * (size_t)N;
#pragma unroll
      for (int nf = 0; nf < 4; ++nf) {
        const int gcol = n0 + wn*64 + nf*16 + l15;
        float v = acc[mf][nf][r] + bias[gcol];
        if constexpr (MODE == 1)
          v = 0.5f * v * (1.0f + erff(v * 0.70710678118654752440f));
        outb[rowoff + gcol] = (bf16)v;
      }
    }
  }
}

// ---------------------------------------------------------------------------
// GEMM 128x128 (kept for N=1024 GEMMs where 256-tile grids underfill the GPU).
// MODE 2: outf = acc+bias+res (f32)
// ---------------------------------------------------------------------------
template<int MODE>
__global__ __launch_bounds__(256)
void k_gemm(const bf16* __restrict__ A, const bf16* __restrict__ Bt,
            const float* __restrict__ bias, const float* __restrict__ res,
            bf16* __restrict__ outb, float* __restrict__ outf,
            int M, int N, int K) {
  __shared__ __align__(16) bf16 As[128 * 64];
  __shared__ __align__(16) bf16 Bs[128 * 64];
  const int tid = threadIdx.x;
  const int w = tid >> 6, l = tid & 63;
  const int wm = w >> 1, wn = w & 1;
  const int l15 = l & 15, l4 = l >> 4;
  const int m0 = blockIdx.y * 128, n0 = blockIdx.x * 128;

  f32x4 acc[4][4] = {};

  const int srow0 = w * 32 + (l >> 3);
  const int sl7 = l & 7;

  for (int k0 = 0; k0 < K; k0 += 64) {
#pragma unroll
    for (int j = 0; j < 4; ++j) {
      const int row = srow0 + j * 8;
      const int ch = sl7 ^ (row & 7);
      async_ld16(A + (size_t)(m0 + row) * K + k0 + ch * 8, &As[(w*32 + j*8) * 64]);
    }
#pragma unroll
    for (int j = 0; j < 4; ++j) {
      const int row = srow0 + j * 8;
      const int ch = sl7 ^ (row & 7);
      async_ld16(Bt + (size_t)(n0 + row) * K + k0 + ch * 8, &Bs[(w*32 + j*8) * 64]);
    }
    __syncthreads();
#pragma unroll
    for (int kk = 0; kk < 2; ++kk) {
      bf16x8 af[4], bfr[4];
#pragma unroll
      for (int mf = 0; mf < 4; ++mf) {
        const int row = wm*64 + mf*16 + l15;
        const int ch = (kk*4 + l4) ^ (row & 7);
        af[mf] = *(const bf16x8*)&As[row*64 + ch*8];
      }
#pragma unroll
      for (int nf = 0; nf < 4; ++nf) {
        const int row = wn*64 + nf*16 + l15;
        const int ch = (kk*4 + l4) ^ (row & 7);
        bfr[nf] = *(const bf16x8*)&Bs[row*64 + ch*8];
      }
#pragma unroll
      for (int mf = 0; mf < 4; ++mf)
#pragma unroll
        for (int nf = 0; nf < 4; ++nf)
          acc[mf][nf] = __builtin_amdgcn_mfma_f32_16x16x32_bf16(af[mf], bfr[nf], acc[mf][nf], 0, 0, 0);
    }
    __syncthreads();
  }

#pragma unroll
  for (int mf = 0; mf < 4; ++mf) {
#pragma unroll
    for (int r = 0; r < 4; ++r) {
      const size_t grow = (size_t)(m0 + wm*64 + mf*16 + l4*4 + r);
      const size_t rowoff = grow * (size_t)N;
#pragma unroll
      for (int nf = 0; nf < 4; ++nf) {
        const int gcol = n0 + wn*64 + nf*16 + l15;
        float v = acc[mf][nf][r] + bias[gcol];
        if constexpr (MODE == 1)
          v = 0.5f * v * (1.0f + erff(v * 0.70710678118654752440f));
        if constexpr (MODE == 2) {
          v += res[rowoff + gcol];
          outf[rowoff + gcol] = v;
        } else {
          outb[rowoff + gcol] = (bf16)v;
        }
      }
    }
  }
}

// ---------------------------------------------------------------------------
// Flash attention v2. qkv: (B*T, 3072) bf16 rows = [Q | K | V]; vT[b][h][e][t].
// ---------------------------------------------------------------------------
__global__ __launch_bounds__(256)
void k_attn(const bf16* __restrict__ qkv, const bf16* __restrict__ vT,
            bf16* __restrict__ ctx) {
  const int qt = blockIdx.x, h = blockIdx.y, b = blockIdx.z;
  const int tid = threadIdx.x;
  const int w = tid >> 6, l = tid & 63;
  const int l15 = l & 15, l4 = l >> 4;

  __shared__ __align__(16) bf16 Ks[2][64 * 64];   // [kv][hd] swizzled
  __shared__ __align__(16) bf16 Vs[2][64 * 64];   // [e][kv]  swizzled
  __shared__ __align__(16) bf16 P[4][16][72];     // wave-private P[q][kv]

  const bf16* base = qkv + (size_t)b * TT * 3072;
  const bf16* Qp = base + h * 64;
  const bf16* Kp = base + 1024 + h * 64;
  const bf16* Vtp = vT + ((size_t)(b * HH + h)) * HDIM * TT;

  const int qrow = qt * 64 + w * 16 + l15;
  bf16x8 qf[2];
  qf[0] = *(const bf16x8*)&Qp[(size_t)qrow * 3072 + l4 * 8];
  qf[1] = *(const bf16x8*)&Qp[(size_t)qrow * 3072 + 32 + l4 * 8];

  f32x4 oacc[4] = {};
  float mrow[4] = {-1e30f, -1e30f, -1e30f, -1e30f};
  float lrow[4] = {0.f, 0.f, 0.f, 0.f};

  const int sr = (l >> 3);
  const int sl7 = l & 7;

  auto stage = [&](int buf, int t) {
    const int kv0 = t * 64;
#pragma unroll
    for (int j = 0; j < 2; ++j) {
      const int row = w*16 + j*8 + sr;
      const int ch = sl7 ^ (row & 7);
      async_ld16(Kp + (size_t)(kv0 + row) * 3072 + ch * 8, &Ks[buf][(w*16 + j*8) * 64]);
    }
#pragma unroll
    for (int j = 0; j < 2; ++j) {
      const int row = w*16 + j*8 + sr;
      const int ch = sl7 ^ (row & 7);
      async_ld16(Vtp + (size_t)row * TT + kv0 + ch * 8, &Vs[buf][(w*16 + j*8) * 64]);
    }
  };

  stage(0, 0);
  for (int t = 0; t < TT / 64; ++t) {
    const int cur = t & 1;
    __syncthreads();
    if (t + 1 < TT / 64) stage(cur ^ 1, t + 1);

    f32x4 sacc[4] = {};
#pragma unroll
    for (int nf = 0; nf < 4; ++nf) {
      const int row = nf*16 + l15;
#pragma unroll
      for (int kk = 0; kk < 2; ++kk) {
        const int ch = (kk*4 + l4) ^ (row & 7);
        bf16x8 kfr = *(const bf16x8*)&Ks[cur][row*64 + ch*8];
        sacc[nf] = __builtin_amdgcn_mfma_f32_16x16x32_bf16(qf[kk], kfr, sacc[nf], 0, 0, 0);
      }
    }
    float mnew[4], ef[4];
#pragma unroll
    for (int r = 0; r < 4; ++r) {
      float mx = -1e30f;
#pragma unroll
      for (int nf = 0; nf < 4; ++nf) { sacc[nf][r] *= 0.125f; mx = fmaxf(mx, sacc[nf][r]); }
      mx = fmaxf(mx, __shfl_xor(mx, 1));
      mx = fmaxf(mx, __shfl_xor(mx, 2));
      mx = fmaxf(mx, __shfl_xor(mx, 4));
      mx = fmaxf(mx, __shfl_xor(mx, 8));
      mnew[r] = fmaxf(mrow[r], mx);
      ef[r] = __expf(mrow[r] - mnew[r]);
      mrow[r] = mnew[r];
    }
#pragma unroll
    for (int r = 0; r < 4; ++r) {
      float rs = 0.f;
#pragma unroll
      for (int nf = 0; nf < 4; ++nf) {
        const float p = __expf(sacc[nf][r] - mnew[r]);
        rs += p;
        P[w][l4*4 + r][l15 + nf*16] = (bf16)p;
      }
      rs += __shfl_xor(rs, 1); rs += __shfl_xor(rs, 2);
      rs += __shfl_xor(rs, 4); rs += __shfl_xor(rs, 8);
      lrow[r] = lrow[r] * ef[r] + rs;
#pragma unroll
      for (int nf = 0; nf < 4; ++nf) oacc[nf][r] *= ef[r];
    }
#pragma unroll
    for (int kk = 0; kk < 2; ++kk) {
      bf16x8 pa = *(const bf16x8*)&P[w][l15][kk*32 + l4*8];
#pragma unroll
      for (int nf = 0; nf < 4; ++nf) {
        const int row = nf*16 + l15;
        const int ch = (kk*4 + l4) ^ (row & 7);
        bf16x8 vb = *(const bf16x8*)&Vs[cur][row*64 + ch*8];
        oacc[nf] = __builtin_amdgcn_mfma_f32_16x16x32_bf16(pa, vb, oacc[nf], 0, 0, 0);
      }
    }
  }
  bf16* outp = ctx + ((size_t)b * TT + qt * 64 + w * 16) * DD + h * 64;
#pragma unroll
  for (int nf = 0; nf < 4; ++nf)
#pragma unroll
    for (int r = 0; r < 4; ++r)
      outp[(size_t)(l4*4 + r) * DD + l15 + nf*16] = (bf16)(oacc[nf][r] / lrow[r]);
}

// ---------------------------------------------------------------------------
// launch
// ---------------------------------------------------------------------------
extern "C" void kernel_launch(void* const* d_in, const int* in_sizes, int n_in,
                              void* d_out, int out_size, void* d_ws, size_t ws_size,
                              hipStream_t stream) {
  const float* x     = (const float*)d_in[0];
  const float* ln1_g = (const float*)d_in[1];
  const float* ln1_b = (const float*)d_in[2];
  const float* ln2_g = (const float*)d_in[3];
  const float* ln2_b = (const float*)d_in[4];
  const float* Wq    = (const float*)d_in[5];
  const float* bq    = (const float*)d_in[6];
  const float* Wk    = (const float*)d_in[7];
  const float* bk    = (const float*)d_in[8];
  const float* Wv    = (const float*)d_in[9];
  const float* bv    = (const float*)d_in[10];
  const float* Wo    = (const float*)d_in[11];
  const float* bo    = (const float*)d_in[12];
  const float* W1    = (const float*)d_in[13];
  const float* b1    = (const float*)d_in[14];
  const float* W2    = (const float*)d_in[15];
  const float* b2    = (const float*)d_in[16];
  float* out = (float*)d_out;

  char* ws = (char*)d_ws;
  bf16* h1    = (bf16*)(ws + 0);                    // 16MB, LN1 out (dead after QKV GEMM)
  bf16* vT    = (bf16*)(ws + 0);                    // 16MB, aliases h1
  bf16* qkv   = (bf16*)(ws + 16777216);             // 48MB
  bf16* ctx   = (bf16*)(ws + 67108864);             // 16MB
  bf16* u     = (bf16*)(ws + 16777216);             // 64MB, aliases qkv+ctx (dead)
  float* x1   = (float*)(ws + 83886080);            // 32MB
  bf16* wtqkv = (bf16*)(ws + 117440512);            // 6MB  (3072,1024)
  bf16* wot   = (bf16*)(ws + 123731968);            // 2MB  (1024,1024)
  bf16* w1t   = (bf16*)(ws + 125829120);            // 8MB  (4096,1024)
  bf16* w2t   = (bf16*)(ws + 134217728);            // 8MB  (1024,4096)
  float* bqkv = (float*)(ws + 142606336);           // 12KB (3072)
  bf16* h2 = h1;

  dim3 tb(32, 8);
  k_transpose_cast<<<dim3(2, 32, 16), tb, 0, stream>>>(Wq, wtqkv, DD, HDIM);
  k_transpose_cast<<<dim3(2, 32, 16), tb, 0, stream>>>(Wk, wtqkv + 1024*1024, DD, HDIM);
  k_transpose_cast<<<dim3(2, 32, 16), tb, 0, stream>>>(Wv, wtqkv + 2048*1024, DD, HDIM);
  k_transpose_cast<<<dim3(32, 32, 1), tb, 0, stream>>>(Wo, wot, DD, DD);
  k_transpose_cast<<<dim3(128, 32, 1), tb, 0, stream>>>(W1, w1t, DD, FFD);
  k_transpose_cast<<<dim3(32, 128, 1), tb, 0, stream>>>(W2, w2t, FFD, DD);
  k_concat_bias<<<dim3(12), 256, 0, stream>>>(bq, bk, bv, bqkv);

  k_layernorm<<<dim3(MROWS), 256, 0, stream>>>(x, ln1_g, ln1_b, h1);

  // QKV: (8192,1024) x (3072,1024)^T -> qkv bf16   [256-tile 8-phase]
  k_gemm256<0><<<dim3((MROWS/256)*(3072/256)), 512, 0, stream>>>(
      h1, wtqkv, bqkv, qkv, MROWS, 3072, DD);

  k_transpose_v<<<dim3(32, 2, 128), tb, 0, stream>>>(qkv, vT);

  k_attn<<<dim3(16, 16, 8), 256, 0, stream>>>(qkv, vT, ctx);

  // Wo + residual: x1 = x + ctx@Wo + bo  (f32)  [128-tile: N=1024 grid-fill]
  k_gemm<2><<<dim3(8, 64), 256, 0, stream>>>(ctx, wot, bo, x,
                                             nullptr, x1, MROWS, DD, DD);

  k_layernorm<<<dim3(MROWS), 256, 0, stream>>>(x1, ln2_g, ln2_b, h2);

  // FF1 + exact GELU -> u bf16   [256-tile 8-phase]
  k_gemm256<1><<<dim3((MROWS/256)*(FFD/256)), 512, 0, stream>>>(
      h2, w1t, b1, u, MROWS, FFD, DD);

  // FF2 + residual -> out f32  [128-tile: N=1024 grid-fill]
  k_gemm<2><<<dim3(8, 64), 256, 0, stream>>>(u, w2t, b2, x1,
                                             nullptr, out, MROWS, DD, FFD);

  (void)in_sizes; (void)n_in; (void)out_size; (void)ws_size;
}

// Round 4
// 443.840 us; speedup vs baseline: 1.1980x; 1.0640x over previous
//
#include <hip/hip_runtime.h>
#include <hip/hip_bf16.h>
#include <cstdint>
#include <cstddef>

// ---------------------------------------------------------------------------
// Transformer block: LN1 -> MHA(16 heads, no mask) -> +res -> LN2 -> GELU MLP -> +res
// B=8 T=1024 D=1024 H=16 HD=64 FF=4096.  bf16 MFMA everywhere, fp32 accum.
// ---------------------------------------------------------------------------

typedef __bf16 bf16;
typedef __bf16 bf16x8 __attribute__((ext_vector_type(8)));
typedef __bf16 bf16x4 __attribute__((ext_vector_type(4)));
typedef float  f32x4  __attribute__((ext_vector_type(4)));

#define BB    8
#define TT    1024
#define DD    1024
#define HH    16
#define HDIM  64
#define FFD   4096
#define MROWS (BB*TT)   // 8192

// async global->LDS, 16B per lane, LDS dest = wave-uniform base + lane*16
__device__ __forceinline__ void async_ld16(const void* g, void* l) {
  __builtin_amdgcn_global_load_lds(
      (const __attribute__((address_space(1))) uint32_t*)g,
      (__attribute__((address_space(3))) uint32_t*)l, 16, 0, 0);
}

// ---------------------------------------------------------------------------
// Weight repack: src (K,N) f32 row-major -> dst (N,K) bf16 row-major (B^T),
// batched over blockIdx.z (per-head for Wq/Wk/Wv).
// ---------------------------------------------------------------------------
__global__ void k_transpose_cast(const float* __restrict__ src, bf16* __restrict__ dst,
                                 int K, int N) {
  __shared__ float tile[32][33];
  const size_t boff = (size_t)blockIdx.z * K * N;
  src += boff; dst += boff;
  const int k0 = blockIdx.y * 32, n0 = blockIdx.x * 32;
  const int tx = threadIdx.x, ty = threadIdx.y; // (32,8)
#pragma unroll
  for (int i = 0; i < 4; ++i)
    tile[ty + i*8][tx] = src[(size_t)(k0 + ty + i*8) * N + n0 + tx];
  __syncthreads();
#pragma unroll
  for (int i = 0; i < 4; ++i)
    dst[(size_t)(n0 + ty + i*8) * K + k0 + tx] = (bf16)tile[tx][ty + i*8];
}

__global__ void k_concat_bias(const float* __restrict__ bq, const float* __restrict__ bk,
                              const float* __restrict__ bv, float* __restrict__ out) {
  int i = blockIdx.x * 256 + threadIdx.x; // 3072
  float v = (i < 1024) ? bq[i] : (i < 2048) ? bk[i - 1024] : bv[i - 2048];
  out[i] = v;
}

// V part of qkv (B*T, 3072) -> vT[b][h][e][t]  (per-(b,h) 64x1024, t contiguous)
__global__ void k_transpose_v(const bf16* __restrict__ qkv, bf16* __restrict__ vT) {
  __shared__ bf16 tile[32][33];
  const int bh = blockIdx.z;          // b*16+h
  const int b = bh >> 4, h = bh & 15;
  const int t0 = blockIdx.x * 32, e0 = blockIdx.y * 32;
  const int tx = threadIdx.x, ty = threadIdx.y; // (32,8)
  const bf16* src = qkv + (size_t)b * TT * 3072 + 2048 + h * 64;
#pragma unroll
  for (int i = 0; i < 4; ++i)
    tile[ty + i*8][tx] = src[(size_t)(t0 + ty + i*8) * 3072 + e0 + tx];
  __syncthreads();
  bf16* dst = vT + ((size_t)bh * 64 + e0) * TT + t0;
#pragma unroll
  for (int i = 0; i < 4; ++i)
    dst[(size_t)(ty + i*8) * TT + tx] = tile[tx][ty + i*8];
}

// ---------------------------------------------------------------------------
// LayerNorm: one block per row (D=1024), 256 threads, f32 in -> bf16 out
// ---------------------------------------------------------------------------
__global__ void k_layernorm(const float* __restrict__ x, const float* __restrict__ g,
                            const float* __restrict__ b, bf16* __restrict__ out) {
  const int row = blockIdx.x, tid = threadIdx.x;
  const float* xr = x + (size_t)row * DD;
  f32x4 v = *(const f32x4*)(xr + tid * 4);
  float s  = v[0] + v[1] + v[2] + v[3];
  float ss = v[0]*v[0] + v[1]*v[1] + v[2]*v[2] + v[3]*v[3];
#pragma unroll
  for (int m = 1; m < 64; m <<= 1) { s += __shfl_xor(s, m); ss += __shfl_xor(ss, m); }
  __shared__ float red[8];
  const int wid = tid >> 6;
  if ((tid & 63) == 0) { red[wid*2] = s; red[wid*2+1] = ss; }
  __syncthreads();
  s  = red[0] + red[2] + red[4] + red[6];
  ss = red[1] + red[3] + red[5] + red[7];
  const float mu = s * (1.0f / DD);
  const float var = ss * (1.0f / DD) - mu * mu;
  const float rs = rsqrtf(var + 1e-5f);
  bf16x4 o;
#pragma unroll
  for (int j = 0; j < 4; ++j)
    o[j] = (bf16)((v[j] - mu) * rs * g[tid*4 + j] + b[tid*4 + j]);
  *(bf16x4*)&out[(size_t)row * DD + tid * 4] = o;
}

// ---------------------------------------------------------------------------
// 256x256-tile 8-wave phase-split GEMM v2.  C = A(M,K) * Bt(N,K)^T.
// BK=64, double-buffered LDS (128 KiB), 4 phases/K-tile with PER-PHASE frag
// reads (max 12 live frags -> ~190 VGPR, vs v1's 24-up-front):
//   P1: read b0,a(m0,k0); stage B(t+1)q01; bar; lgkm0; MFMA k0m0; bar
//   P2: read a(m1,k0);    stage B(t+1)q23; bar; lgkm0; MFMA k0m1; bar
//   P3: read b1,a(m0,k1),a(m1,k1);        bar; lgkm0; MFMA k1m0; bar
//       (after this bar, ALL buf[p] reads are drained on every wave)
//   P4: stage A(t+2)q0123 into buf[p];          MFMA k1m1; vmcnt(4); bar
// Boundary vmcnt(4): B(t+1)/A(t+1) arrived, A(t+2) quarters stay in flight.
// MODE 0: outb = acc+bias (bf16);  MODE 1: outb = gelu_exact(acc+bias) (bf16)
// ---------------------------------------------------------------------------
template<int MODE>
__global__ __launch_bounds__(512, 2)
void k_gemm256(const bf16* __restrict__ A, const bf16* __restrict__ Bt,
               const float* __restrict__ bias, bf16* __restrict__ outb,
               int M, int N, int K) {
  __shared__ __align__(16) bf16 As[2][256 * 64];
  __shared__ __align__(16) bf16 Bs[2][256 * 64];
  const int tid = threadIdx.x;
  const int w = tid >> 6, l = tid & 63;
  const int wm = w >> 2, wn = w & 3;            // 2 x 4 waves
  const int l15 = l & 15, l4 = l >> 4;

  // XCD-aware swizzle (nwg % 8 == 0 for all our shapes)
  const int nbx = N >> 8;
  const int nwg = gridDim.x;
  const int cpx = nwg >> 3;
  const int swz = (blockIdx.x & 7) * cpx + (blockIdx.x >> 3);
  const int m0 = (swz / nbx) << 8, n0 = (swz % nbx) << 8;

  f32x4 acc[8][4] = {};

  const int srow = l >> 3;     // 0..7
  const int sch = l & 7;

  const int NT = K >> 6;

#define STAGE_A(buf, kt, rb) { \
    const int r_ = (rb) + w*8 + srow; \
    const int ch_ = sch ^ (r_ & 7); \
    async_ld16(A + (size_t)(m0 + r_) * K + (kt)*64 + ch_*8, &As[buf][((rb) + w*8)*64]); }
#define STAGE_B(buf, kt, rb) { \
    const int r_ = (rb) + w*8 + srow; \
    const int ch_ = sch ^ (r_ & 7); \
    async_ld16(Bt + (size_t)(n0 + r_) * K + (kt)*64 + ch_*8, &Bs[buf][((rb) + w*8)*64]); }

  // prologue: tile0 (all 4 quarters of A,B) + tile1 A-quarters  -> 12 loads
  STAGE_A(0, 0, 0)   STAGE_A(0, 0, 64)  STAGE_A(0, 0, 128) STAGE_A(0, 0, 192)
  STAGE_B(0, 0, 0)   STAGE_B(0, 0, 64)  STAGE_B(0, 0, 128) STAGE_B(0, 0, 192)
  STAGE_A(1, 1, 0)   STAGE_A(1, 1, 64)  STAGE_A(1, 1, 128) STAGE_A(1, 1, 192)
  asm volatile("s_waitcnt vmcnt(4)" ::: "memory");
  __builtin_amdgcn_sched_barrier(0);
  __builtin_amdgcn_s_barrier();

  for (int t = 0; t < NT; ++t) {
    const int p = t & 1;
    bf16x8 b0[4], b1[4], af[4], ag[4];

    // ---- P1: read b0 + a(m0,k0); stage B(t+1) q0,q1 ----
#pragma unroll
    for (int nf = 0; nf < 4; ++nf) {
      const int row = wn*64 + nf*16 + l15;
      b0[nf] = *(const bf16x8*)&Bs[p][row*64 + (l4 ^ (row & 7))*8];
    }
#pragma unroll
    for (int mf = 0; mf < 4; ++mf) {
      const int row = wm*128 + mf*16 + l15;
      af[mf] = *(const bf16x8*)&As[p][row*64 + (l4 ^ (row & 7))*8];
    }
    if (t + 1 < NT) { STAGE_B(p^1, t+1, 0) STAGE_B(p^1, t+1, 64) }
    __builtin_amdgcn_s_barrier();
    asm volatile("s_waitcnt lgkmcnt(0)" ::: "memory");
    __builtin_amdgcn_sched_barrier(0);
    __builtin_amdgcn_s_setprio(1);
#pragma unroll
    for (int mf = 0; mf < 4; ++mf)
#pragma unroll
      for (int nf = 0; nf < 4; ++nf)
        acc[mf][nf] = __builtin_amdgcn_mfma_f32_16x16x32_bf16(af[mf], b0[nf], acc[mf][nf], 0, 0, 0);
    __builtin_amdgcn_s_setprio(0);
    __builtin_amdgcn_s_barrier();

    // ---- P2: read a(m1,k0); stage B(t+1) q2,q3 ----
#pragma unroll
    for (int mf = 0; mf < 4; ++mf) {
      const int row = wm*128 + (mf+4)*16 + l15;
      ag[mf] = *(const bf16x8*)&As[p][row*64 + (l4 ^ (row & 7))*8];
    }
    if (t + 1 < NT) { STAGE_B(p^1, t+1, 128) STAGE_B(p^1, t+1, 192) }
    __builtin_amdgcn_s_barrier();
    asm volatile("s_waitcnt lgkmcnt(0)" ::: "memory");
    __builtin_amdgcn_sched_barrier(0);
    __builtin_amdgcn_s_setprio(1);
#pragma unroll
    for (int mf = 0; mf < 4; ++mf)
#pragma unroll
      for (int nf = 0; nf < 4; ++nf)
        acc[mf+4][nf] = __builtin_amdgcn_mfma_f32_16x16x32_bf16(ag[mf], b0[nf], acc[mf+4][nf], 0, 0, 0);
    __builtin_amdgcn_s_setprio(0);
    __builtin_amdgcn_s_barrier();

    // ---- P3: read b1 + a(m0,k1) + a(m1,k1); MFMA k1m0 ----
#pragma unroll
    for (int nf = 0; nf < 4; ++nf) {
      const int row = wn*64 + nf*16 + l15;
      b1[nf] = *(const bf16x8*)&Bs[p][row*64 + ((4+l4) ^ (row & 7))*8];
    }
#pragma unroll
    for (int mf = 0; mf < 4; ++mf) {
      const int row = wm*128 + mf*16 + l15;
      af[mf] = *(const bf16x8*)&As[p][row*64 + ((4+l4) ^ (row & 7))*8];
    }
#pragma unroll
    for (int mf = 0; mf < 4; ++mf) {
      const int row = wm*128 + (mf+4)*16 + l15;
      ag[mf] = *(const bf16x8*)&As[p][row*64 + ((4+l4) ^ (row & 7))*8];
    }
    __builtin_amdgcn_s_barrier();
    asm volatile("s_waitcnt lgkmcnt(0)" ::: "memory");
    __builtin_amdgcn_sched_barrier(0);
    __builtin_amdgcn_s_setprio(1);
#pragma unroll
    for (int mf = 0; mf < 4; ++mf)
#pragma unroll
      for (int nf = 0; nf < 4; ++nf)
        acc[mf][nf] = __builtin_amdgcn_mfma_f32_16x16x32_bf16(af[mf], b1[nf], acc[mf][nf], 0, 0, 0);
    __builtin_amdgcn_s_setprio(0);
    __builtin_amdgcn_s_barrier();   // all buf[p] reads drained on every wave

    // ---- P4: stage A(t+2) into buf[p]; MFMA k1m1; boundary wait ----
    if (t + 2 < NT) { STAGE_A(p, t+2, 0) STAGE_A(p, t+2, 64)
                      STAGE_A(p, t+2, 128) STAGE_A(p, t+2, 192) }
    __builtin_amdgcn_s_setprio(1);
#pragma unroll
    for (int mf = 0; mf < 4; ++mf)
#pragma unroll
      for (int nf = 0; nf < 4; ++nf)
        acc[mf+4][nf] = __builtin_amdgcn_mfma_f32_16x16x32_bf16(ag[mf], b1[nf], acc[mf+4][nf], 0, 0, 0);
    __builtin_amdgcn_s_setprio(0);
    if (t < NT - 2) { asm volatile("s_waitcnt vmcnt(4)" ::: "memory"); }
    else            { asm volatile("s_waitcnt vmcnt(0)" ::: "memory"); }
    __builtin_amdgcn_sched_barrier(0);
    __builtin_amdgcn_s_barrier();   // tile t+1 visible to all waves
  }
#undef STAGE_A
#undef STAGE_B

  // epilogue
#pragma unroll
  for (int mf = 0; mf < 8; ++mf) {
#pragma unroll
    for (int r = 0; r < 4; ++r) {
      const size_t grow = (size_t)(m0 + wm*128 + mf*16 + l4*4 + r);
      const size_t rowoff = grow * (size_t)N;
#pragma unroll
      for (int nf = 0; nf < 4; ++nf) {
        const int gcol = n0 + wn*64 + nf*16 + l15;
        float v = acc[mf][nf][r] + bias[gcol];
        if constexpr (MODE == 1)
          v = 0.5f * v * (1.0f + erff(v * 0.70710678118654752440f));
        outb[rowoff + gcol] = (bf16)v;
      }
    }
  }
}

// ---------------------------------------------------------------------------
// GEMM 128x128 (kept for N=1024 GEMMs where 256-tile grids underfill the GPU).
// MODE 2: outf = acc+bias+res (f32)
// ---------------------------------------------------------------------------
template<int MODE>
__global__ __launch_bounds__(256)
void k_gemm(const bf16* __restrict__ A, const bf16* __restrict__ Bt,
            const float* __restrict__ bias, const float* __restrict__ res,
            bf16* __restrict__ outb, float* __restrict__ outf,
            int M, int N, int K) {
  __shared__ __align__(16) bf16 As[128 * 64];
  __shared__ __align__(16) bf16 Bs[128 * 64];
  const int tid = threadIdx.x;
  const int w = tid >> 6, l = tid & 63;
  const int wm = w >> 1, wn = w & 1;
  const int l15 = l & 15, l4 = l >> 4;
  const int m0 = blockIdx.y * 128, n0 = blockIdx.x * 128;

  f32x4 acc[4][4] = {};

  const int srow0 = w * 32 + (l >> 3);
  const int sl7 = l & 7;

  for (int k0 = 0; k0 < K; k0 += 64) {
#pragma unroll
    for (int j = 0; j < 4; ++j) {
      const int row = srow0 + j * 8;
      const int ch = sl7 ^ (row & 7);
      async_ld16(A + (size_t)(m0 + row) * K + k0 + ch * 8, &As[(w*32 + j*8) * 64]);
    }
#pragma unroll
    for (int j = 0; j < 4; ++j) {
      const int row = srow0 + j * 8;
      const int ch = sl7 ^ (row & 7);
      async_ld16(Bt + (size_t)(n0 + row) * K + k0 + ch * 8, &Bs[(w*32 + j*8) * 64]);
    }
    __syncthreads();
#pragma unroll
    for (int kk = 0; kk < 2; ++kk) {
      bf16x8 af[4], bfr[4];
#pragma unroll
      for (int mf = 0; mf < 4; ++mf) {
        const int row = wm*64 + mf*16 + l15;
        const int ch = (kk*4 + l4) ^ (row & 7);
        af[mf] = *(const bf16x8*)&As[row*64 + ch*8];
      }
#pragma unroll
      for (int nf = 0; nf < 4; ++nf) {
        const int row = wn*64 + nf*16 + l15;
        const int ch = (kk*4 + l4) ^ (row & 7);
        bfr[nf] = *(const bf16x8*)&Bs[row*64 + ch*8];
      }
#pragma unroll
      for (int mf = 0; mf < 4; ++mf)
#pragma unroll
        for (int nf = 0; nf < 4; ++nf)
          acc[mf][nf] = __builtin_amdgcn_mfma_f32_16x16x32_bf16(af[mf], bfr[nf], acc[mf][nf], 0, 0, 0);
    }
    __syncthreads();
  }

#pragma unroll
  for (int mf = 0; mf < 4; ++mf) {
#pragma unroll
    for (int r = 0; r < 4; ++r) {
      const size_t grow = (size_t)(m0 + wm*64 + mf*16 + l4*4 + r);
      const size_t rowoff = grow * (size_t)N;
#pragma unroll
      for (int nf = 0; nf < 4; ++nf) {
        const int gcol = n0 + wn*64 + nf*16 + l15;
        float v = acc[mf][nf][r] + bias[gcol];
        if constexpr (MODE == 1)
          v = 0.5f * v * (1.0f + erff(v * 0.70710678118654752440f));
        if constexpr (MODE == 2) {
          v += res[rowoff + gcol];
          outf[rowoff + gcol] = v;
        } else {
          outb[rowoff + gcol] = (bf16)v;
        }
      }
    }
  }
}

// ---------------------------------------------------------------------------
// Flash attention v3. qkv: (B*T, 3072) bf16 rows = [Q | K | V]; vT[b][h][e][t].
// 512 threads = 8 waves x 16 q-rows = 128 q-rows/block; KV tiles of 64,
// double-buffered swizzled LDS (50 KB -> 3 blocks/CU = 24 waves).
// 1D grid with bijective XCD chunking: 128 consecutive blocks (16 whole (b,h)
// groups) per XCD -> K/V stay L2-resident. Defer-max (T13, THR=8) skips the
// O/l rescale when the running max doesn't grow.
// ---------------------------------------------------------------------------
__global__ __launch_bounds__(512)
void k_attn(const bf16* __restrict__ qkv, const bf16* __restrict__ vT,
            bf16* __restrict__ ctx) {
  const int tid = threadIdx.x;
  const int w = tid >> 6, l = tid & 63;
  const int l15 = l & 15, l4 = l >> 4;

  // nwg = 1024 = 8 qt * 16 h * 8 b; qt fastest in gid
  const int gid = ((int)blockIdx.x & 7) * 128 + ((int)blockIdx.x >> 3);
  const int qt = gid & 7;
  const int bh = gid >> 3;
  const int h = bh & 15, b = bh >> 4;

  __shared__ __align__(16) bf16 Ks[2][64 * 64];   // [kv][hd] swizzled (16 KB)
  __shared__ __align__(16) bf16 Vs[2][64 * 64];   // [e][kv]  swizzled (16 KB)
  __shared__ __align__(16) bf16 P[8][16][72];     // wave-private P[q][kv] (18 KB)

  const bf16* base = qkv + (size_t)b * TT * 3072;
  const bf16* Qp = base + h * 64;
  const bf16* Kp = base + 1024 + h * 64;
  const bf16* Vtp = vT + (size_t)bh * HDIM * TT;

  const int qrow = qt * 128 + w * 16 + l15;
  bf16x8 qf[2];
  qf[0] = *(const bf16x8*)&Qp[(size_t)qrow * 3072 + l4 * 8];
  qf[1] = *(const bf16x8*)&Qp[(size_t)qrow * 3072 + 32 + l4 * 8];

  f32x4 oacc[4] = {};
  float mrow[4] = {-1e30f, -1e30f, -1e30f, -1e30f};
  float lrow[4] = {0.f, 0.f, 0.f, 0.f};

  const int srow = w * 8 + (l >> 3);          // 8 waves cover 64 rows
  const int sch = (l & 7) ^ (srow & 7);

  auto stage = [&](int buf, int t) {
    const int kv0 = t * 64;
    async_ld16(Kp + (size_t)(kv0 + srow) * 3072 + sch * 8, &Ks[buf][w * 512]);
    async_ld16(Vtp + (size_t)srow * TT + kv0 + sch * 8, &Vs[buf][w * 512]);
  };

  stage(0, 0);
  for (int t = 0; t < TT / 64; ++t) {
    const int cur = t & 1;
    __syncthreads();                      // drains stage(t)
    if (t + 1 < TT / 64) stage(cur ^ 1, t + 1);   // flies under compute(t)

    // S = Q K^T
    f32x4 sacc[4] = {};
#pragma unroll
    for (int nf = 0; nf < 4; ++nf) {
      const int row = nf*16 + l15;
#pragma unroll
      for (int kk = 0; kk < 2; ++kk) {
        const int ch = (kk*4 + l4) ^ (row & 7);
        bf16x8 kfr = *(const bf16x8*)&Ks[cur][row*64 + ch*8];
        sacc[nf] = __builtin_amdgcn_mfma_f32_16x16x32_bf16(qf[kk], kfr, sacc[nf], 0, 0, 0);
      }
    }
    // online softmax, C-layout rows (row = 4*l4 + r, col = l15 + 16*nf)
    float mx[4];
    int ok = 1;
#pragma unroll
    for (int r = 0; r < 4; ++r) {
      float m = -1e30f;
#pragma unroll
      for (int nf = 0; nf < 4; ++nf) { sacc[nf][r] *= 0.125f; m = fmaxf(m, sacc[nf][r]); }
      m = fmaxf(m, __shfl_xor(m, 1));
      m = fmaxf(m, __shfl_xor(m, 2));
      m = fmaxf(m, __shfl_xor(m, 4));
      m = fmaxf(m, __shfl_xor(m, 8));
      mx[r] = m;
      ok &= (m <= mrow[r] + 8.0f);
    }
    if (!__all(ok)) {                     // rescale only when max grew (T13)
#pragma unroll
      for (int r = 0; r < 4; ++r) {
        const float mn = fmaxf(mrow[r], mx[r]);
        const float e = __expf(mrow[r] - mn);
        mrow[r] = mn;
        lrow[r] *= e;
#pragma unroll
        for (int nf = 0; nf < 4; ++nf) oacc[nf][r] *= e;
      }
    }
#pragma unroll
    for (int r = 0; r < 4; ++r) {
      float rs = 0.f;
#pragma unroll
      for (int nf = 0; nf < 4; ++nf) {
        const float pv = __expf(sacc[nf][r] - mrow[r]);
        rs += pv;
        P[w][l4*4 + r][l15 + nf*16] = (bf16)pv;
      }
      rs += __shfl_xor(rs, 1); rs += __shfl_xor(rs, 2);
      rs += __shfl_xor(rs, 4); rs += __shfl_xor(rs, 8);
      lrow[r] += rs;
    }
    // O += P * V   (P wave-private; compiler waits lgkmcnt)
#pragma unroll
    for (int kk = 0; kk < 2; ++kk) {
      bf16x8 pa = *(const bf16x8*)&P[w][l15][kk*32 + l4*8];
#pragma unroll
      for (int nf = 0; nf < 4; ++nf) {
        const int row = nf*16 + l15;
        const int ch = (kk*4 + l4) ^ (row & 7);
        bf16x8 vb = *(const bf16x8*)&Vs[cur][row*64 + ch*8];
        oacc[nf] = __builtin_amdgcn_mfma_f32_16x16x32_bf16(pa, vb, oacc[nf], 0, 0, 0);
      }
    }
  }
  // write ctx (B*T, 1024), cols h*64+e
  bf16* outp = ctx + ((size_t)b * TT + qt * 128 + w * 16) * DD + h * 64;
#pragma unroll
  for (int nf = 0; nf < 4; ++nf)
#pragma unroll
    for (int r = 0; r < 4; ++r)
      outp[(size_t)(l4*4 + r) * DD + l15 + nf*16] = (bf16)(oacc[nf][r] / lrow[r]);
}

// ---------------------------------------------------------------------------
// launch
// ---------------------------------------------------------------------------
extern "C" void kernel_launch(void* const* d_in, const int* in_sizes, int n_in,
                              void* d_out, int out_size, void* d_ws, size_t ws_size,
                              hipStream_t stream) {
  const float* x     = (const float*)d_in[0];
  const float* ln1_g = (const float*)d_in[1];
  const float* ln1_b = (const float*)d_in[2];
  const float* ln2_g = (const float*)d_in[3];
  const float* ln2_b = (const float*)d_in[4];
  const float* Wq    = (const float*)d_in[5];
  const float* bq    = (const float*)d_in[6];
  const float* Wk    = (const float*)d_in[7];
  const float* bk    = (const float*)d_in[8];
  const float* Wv    = (const float*)d_in[9];
  const float* bv    = (const float*)d_in[10];
  const float* Wo    = (const float*)d_in[11];
  const float* bo    = (const float*)d_in[12];
  const float* W1    = (const float*)d_in[13];
  const float* b1    = (const float*)d_in[14];
  const float* W2    = (const float*)d_in[15];
  const float* b2    = (const float*)d_in[16];
  float* out = (float*)d_out;

  char* ws = (char*)d_ws;
  bf16* h1    = (bf16*)(ws + 0);                    // 16MB, LN1 out (dead after QKV GEMM)
  bf16* vT    = (bf16*)(ws + 0);                    // 16MB, aliases h1
  bf16* qkv   = (bf16*)(ws + 16777216);             // 48MB
  bf16* ctx   = (bf16*)(ws + 67108864);             // 16MB
  bf16* u     = (bf16*)(ws + 16777216);             // 64MB, aliases qkv+ctx (dead)
  float* x1   = (float*)(ws + 83886080);            // 32MB
  bf16* wtqkv = (bf16*)(ws + 117440512);            // 6MB  (3072,1024)
  bf16* wot   = (bf16*)(ws + 123731968);            // 2MB  (1024,1024)
  bf16* w1t   = (bf16*)(ws + 125829120);            // 8MB  (4096,1024)
  bf16* w2t   = (bf16*)(ws + 134217728);            // 8MB  (1024,4096)
  float* bqkv = (float*)(ws + 142606336);           // 12KB (3072)
  bf16* h2 = h1;

  dim3 tb(32, 8);
  k_transpose_cast<<<dim3(2, 32, 16), tb, 0, stream>>>(Wq, wtqkv, DD, HDIM);
  k_transpose_cast<<<dim3(2, 32, 16), tb, 0, stream>>>(Wk, wtqkv + 1024*1024, DD, HDIM);
  k_transpose_cast<<<dim3(2, 32, 16), tb, 0, stream>>>(Wv, wtqkv + 2048*1024, DD, HDIM);
  k_transpose_cast<<<dim3(32, 32, 1), tb, 0, stream>>>(Wo, wot, DD, DD);
  k_transpose_cast<<<dim3(128, 32, 1), tb, 0, stream>>>(W1, w1t, DD, FFD);
  k_transpose_cast<<<dim3(32, 128, 1), tb, 0, stream>>>(W2, w2t, FFD, DD);
  k_concat_bias<<<dim3(12), 256, 0, stream>>>(bq, bk, bv, bqkv);

  k_layernorm<<<dim3(MROWS), 256, 0, stream>>>(x, ln1_g, ln1_b, h1);

  // QKV: (8192,1024) x (3072,1024)^T -> qkv bf16   [256-tile phase-split v2]
  k_gemm256<0><<<dim3((MROWS/256)*(3072/256)), 512, 0, stream>>>(
      h1, wtqkv, bqkv, qkv, MROWS, 3072, DD);

  k_transpose_v<<<dim3(32, 2, 128), tb, 0, stream>>>(qkv, vT);

  k_attn<<<dim3(1024), 512, 0, stream>>>(qkv, vT, ctx);

  // Wo + residual: x1 = x + ctx@Wo + bo  (f32)  [128-tile: N=1024 grid-fill]
  k_gemm<2><<<dim3(8, 64), 256, 0, stream>>>(ctx, wot, bo, x,
                                             nullptr, x1, MROWS, DD, DD);

  k_layernorm<<<dim3(MROWS), 256, 0, stream>>>(x1, ln2_g, ln2_b, h2);

  // FF1 + exact GELU -> u bf16   [256-tile phase-split v2]
  k_gemm256<1><<<dim3((MROWS/256)*(FFD/256)), 512, 0, stream>>>(
      h2, w1t, b1, u, MROWS, FFD, DD);

  // FF2 + residual -> out f32  [128-tile: N=1024 grid-fill]
  k_gemm<2><<<dim3(8, 64), 256, 0, stream>>>(u, w2t, b2, x1,
                                             nullptr, out, MROWS, DD, FFD);

  (void)in_sizes; (void)n_in; (void)out_size; (void)ws_size;
}